// Round 1
// baseline (177.494 us; speedup 1.0000x reference)
//
#include <hip/hip_runtime.h>

#define NB 32      // B
#define NS 8192    // S
#define NH 256     // H
#define NR 256     // RIN
#define NQ 256     // QIN

typedef __bf16 bf16x8 __attribute__((ext_vector_type(8)));
typedef float  f32x4  __attribute__((ext_vector_type(4)));

__device__ __forceinline__ float fast_tanh(float x) {
  // tanh(x) = (e^{2x}-1)/(e^{2x}+1); clamp: tanh(|x|>=15) == 1.0f in f32 exactly
  x = fminf(15.0f, fmaxf(-15.0f, x));
  float e = __expf(2.0f * x);
  return (e - 1.0f) * __builtin_amdgcn_rcpf(e + 1.0f);
}

// split 8 consecutive f32 into bf16 hi + bf16 lo (RNE): x ~= hi + lo, |err| ~ 2^-16 rel
__device__ __forceinline__ void split8(float4 a, float4 b, bf16x8& hi, bf16x8& lo) {
  float x[8] = {a.x, a.y, a.z, a.w, b.x, b.y, b.z, b.w};
#pragma unroll
  for (int j = 0; j < 8; ++j) {
    __bf16 h = (__bf16)x[j];
    hi[j] = h;
    lo[j] = (__bf16)(x[j] - (float)h);
  }
}

// blocks 0..31: q[b,h] = query[b,:]@Wq[h,:] + bq[h]
// blocks 32..63: split Wr into fragment-linear hi/lo bf16: [ks][mtile][lane][8]
//   element = Wr[16*mt + (l&15)][32*ks + 8*(l>>4) + j]  (A-frag layout of mfma 16x16x32)
__global__ __launch_bounds__(256) void prep_kernel(
    const float* __restrict__ query, const float* __restrict__ Wq,
    const float* __restrict__ bq, const float* __restrict__ Wr,
    float* __restrict__ ws_q, __bf16* __restrict__ wsAhi, __bf16* __restrict__ wsAlo) {
  const int tid = threadIdx.x;
  const int blk = blockIdx.x;
  if (blk < NB) {
    const float4* qr = reinterpret_cast<const float4*>(query + blk * NQ);
    const float4* wr = reinterpret_cast<const float4*>(Wq + tid * NQ);
    float acc = 0.0f;
#pragma unroll 8
    for (int i = 0; i < NQ / 4; ++i) {
      float4 a = qr[i], w = wr[i];
      acc += a.x * w.x + a.y * w.y + a.z * w.z + a.w * w.w;
    }
    ws_q[blk * NH + tid] = acc + bq[tid];
  } else {
    const int gid = (blk - NB) * 256 + tid;   // 0..8191 = [ks(8)][mt(16)][lane(64)]
    const int l  = gid & 63;
    const int mt = (gid >> 6) & 15;
    const int ks = gid >> 10;
    const int row = 16 * mt + (l & 15);
    const int kb  = 32 * ks + 8 * (l >> 4);
    const float4* src = reinterpret_cast<const float4*>(Wr + row * NR + kb);
    bf16x8 hi, lo;
    split8(src[0], src[1], hi, lo);
    *reinterpret_cast<bf16x8*>(wsAhi + (size_t)gid * 8) = hi;
    *reinterpret_cast<bf16x8*>(wsAlo + (size_t)gid * 8) = lo;
  }
}

// One block: batch b, s-tile of 64 cols, ALL 256 h rows. 4 waves, wave wm = h rows [64wm,64wm+64).
// e = Wr @ X (X[r,s] = ref[s,b,r]) via 3x bf16-split MFMA; epilogue fuses +br, e-store, tanh, u-reduce.
__global__ __launch_bounds__(256, 2) void attn_kernel(
    const float* __restrict__ ref, const float* __restrict__ br,
    const float* __restrict__ v, const float* __restrict__ ws_q,
    const __bf16* __restrict__ wsAhi, const __bf16* __restrict__ wsAlo,
    float* __restrict__ e_out, float* __restrict__ u_out) {
  __shared__ __bf16 lXhi[4 * 64 * 8];   // frag-linear: [ntile(4)][lane(64)][8]
  __shared__ __bf16 lXlo[4 * 64 * 8];
  __shared__ float  u_part[4][64];

  const int tid = threadIdx.x;
  const int l   = tid & 63;
  const int wm  = tid >> 6;            // wave id == h-block == staging n-tile
  const int s0  = blockIdx.x * 64;
  const int b   = blockIdx.y;

  // staging source: thread stages slot (nt=wm, lane=l): 8 consecutive r of one s-row
  const float* srcX = ref + (size_t)(s0 + 16 * wm + (l & 15)) * (NB * NR)
                          + (size_t)b * NR + 8 * (l >> 4);

  f32x4 acc[4][4];
  const f32x4 zero = {0.f, 0.f, 0.f, 0.f};
#pragma unroll
  for (int mt = 0; mt < 4; ++mt)
#pragma unroll
    for (int nt = 0; nt < 4; ++nt) acc[mt][nt] = zero;

#pragma unroll 1
  for (int ks = 0; ks < NR / 32; ++ks) {
    // A-frags for this k-step: coalesced dwordx4 from L2-resident pre-split Wr
    bf16x8 ah[4], al[4];
#pragma unroll
    for (int mt = 0; mt < 4; ++mt) {
      const size_t fo = ((size_t)(ks * 16 + wm * 4 + mt) * 64 + l) * 8;
      ah[mt] = *reinterpret_cast<const bf16x8*>(wsAhi + fo);
      al[mt] = *reinterpret_cast<const bf16x8*>(wsAlo + fo);
    }
    __syncthreads();                       // previous step's B-frag reads done
    float4 x0 = *reinterpret_cast<const float4*>(srcX + ks * 32);
    float4 x1 = *reinterpret_cast<const float4*>(srcX + ks * 32 + 4);
    bf16x8 xhi, xlo;
    split8(x0, x1, xhi, xlo);
    *reinterpret_cast<bf16x8*>(lXhi + tid * 8) = xhi;
    *reinterpret_cast<bf16x8*>(lXlo + tid * 8) = xlo;
    __syncthreads();

    bf16x8 bh[4], bl[4];
#pragma unroll
    for (int nt = 0; nt < 4; ++nt) {       // contiguous ds_read_b128, conflict-free
      bh[nt] = *reinterpret_cast<const bf16x8*>(lXhi + (nt * 64 + l) * 8);
      bl[nt] = *reinterpret_cast<const bf16x8*>(lXlo + (nt * 64 + l) * 8);
    }
#pragma unroll
    for (int mt = 0; mt < 4; ++mt) {
#pragma unroll
      for (int nt = 0; nt < 4; ++nt) {
        acc[mt][nt] = __builtin_amdgcn_mfma_f32_16x16x32_bf16(ah[mt], bh[nt], acc[mt][nt], 0, 0, 0);
        acc[mt][nt] = __builtin_amdgcn_mfma_f32_16x16x32_bf16(ah[mt], bl[nt], acc[mt][nt], 0, 0, 0);
        acc[mt][nt] = __builtin_amdgcn_mfma_f32_16x16x32_bf16(al[mt], bh[nt], acc[mt][nt], 0, 0, 0);
      }
    }
  }

  // Epilogue. C/D layout (m89-verified): col = lane&15, row = 4*(lane>>4) + reg
  const int col = l & 15;
  const int rq  = l >> 4;
  float psum[4] = {0.f, 0.f, 0.f, 0.f};
#pragma unroll
  for (int mt = 0; mt < 4; ++mt) {
#pragma unroll
    for (int r = 0; r < 4; ++r) {
      const int h = 64 * wm + 16 * mt + 4 * rq + r;
      const float brv = br[h];
      const float qv  = ws_q[b * NH + h];
      const float vv  = v[h];
#pragma unroll
      for (int nt = 0; nt < 4; ++nt) {
        float e = acc[mt][nt][r] + brv;
        e_out[(size_t)b * NH * NS + (size_t)h * NS + (s0 + 16 * nt + col)] = e;
        psum[nt] += vv * fast_tanh(qv + e);
      }
    }
  }
  // reduce over h: butterfly over the 4 lane-quads, then deterministic cross-wave sum
#pragma unroll
  for (int nt = 0; nt < 4; ++nt) {
    float p = psum[nt];
    p += __shfl_xor(p, 16, 64);
    p += __shfl_xor(p, 32, 64);
    if (l < 16) u_part[wm][16 * nt + col] = p;
  }
  __syncthreads();
  if (tid < 64) {
    float u = u_part[0][tid] + u_part[1][tid] + u_part[2][tid] + u_part[3][tid];
    u_out[(size_t)b * NS + s0 + tid] = 10.0f * fast_tanh(u);
  }
}

extern "C" void kernel_launch(void* const* d_in, const int* in_sizes, int n_in,
                              void* d_out, int out_size, void* d_ws, size_t ws_size,
                              hipStream_t stream) {
  const float* query = (const float*)d_in[0];
  const float* ref   = (const float*)d_in[1];
  const float* Wq    = (const float*)d_in[2];
  const float* bq    = (const float*)d_in[3];
  const float* Wr    = (const float*)d_in[4];
  const float* br    = (const float*)d_in[5];
  const float* v     = (const float*)d_in[6];

  float* e_out = (float*)d_out;                       // [B][H][S]
  float* u_out = e_out + (size_t)NB * NH * NS;        // [B][S]

  // ws layout: q f32[32][256] (32 KiB) | Wr hi bf16[8192*8] (128 KiB) | Wr lo (128 KiB)
  float*  ws_q  = (float*)d_ws;
  __bf16* wsAhi = (__bf16*)((char*)d_ws + 32 * 1024);
  __bf16* wsAlo = (__bf16*)((char*)d_ws + 32 * 1024 + 128 * 1024);

  prep_kernel<<<dim3(NB + 32), 256, 0, stream>>>(query, Wq, bq, Wr, ws_q, wsAhi, wsAlo);
  attn_kernel<<<dim3(NS / 64, NB), 256, 0, stream>>>(ref, br, v, ws_q, wsAhi, wsAlo, e_out, u_out);
}